// Round 3
// baseline (554.185 us; speedup 1.0000x reference)
//
#include <hip/hip_runtime.h>
#include <hip/hip_fp16.h>

// Fixed problem shape
#define TOK   64
#define INF   4096
#define OUTF  11008
#define NUMEL (OUTF * INF)      // 45088768
#define NQB   (NUMEL / 1024)    // 44032 quant blocks
#define NBLK  (OUTF / 16)       // 688 GEMM blocks

// Harness dtypes: fp16 arrays arrive as fp32; ints as int32; output fp32.
typedef __attribute__((ext_vector_type(8))) _Float16 half8;
typedef __attribute__((ext_vector_type(4))) _Float16 half4;
typedef __attribute__((ext_vector_type(4))) float floatx4;

// ---------------------------------------------------------------------------
// Precompute: (a) x fp32 -> fp16 (512 KB, stays L2-resident for the GEMM),
// (b) cum[b] = #outliers with pos < b*1024  (lower_bound on sorted fp16_pos).
// With cum[], int8_pos (180 MB) is never read: i = p - (#outliers < p).
// ---------------------------------------------------------------------------
__global__ __launch_bounds__(256) void precompute_kernel(
    const float* __restrict__ x, const int* __restrict__ fppos, int nf,
    _Float16* __restrict__ x16, int* __restrict__ cum) {
  const int t = blockIdx.x * 256 + threadIdx.x;
  if (t < (TOK * INF) / 4) {
    const floatx4 f = *(const floatx4*)&x[t * 4];
    half4 h;
    h[0] = (_Float16)f[0]; h[1] = (_Float16)f[1];
    h[2] = (_Float16)f[2]; h[3] = (_Float16)f[3];
    *(half4*)&x16[t * 4] = h;
  }
  if (t <= NQB) {
    const int target = t << 10;
    int lo = 0, hi = nf;  // first index with fppos[idx] >= target
    while (lo < hi) {
      const int mid = (lo + hi) >> 1;
      if (fppos[mid] < target) lo = mid + 1; else hi = mid;
    }
    cum[t] = lo;
  }
}

// ---------------------------------------------------------------------------
// Fused dequant + GEMM: out = x @ W^T + bias, W never materialized.
// Grid 688: block owns output features [n0, n0+16). 4 waves; wave w owns
// K-range [1024w, 1024w+1024) -> for lane's row r = n0 + (lane&15), that
// K-stripe is EXACTLY quant block b = 4r + w (scale & outlier state are
// loop-invariant). Wave computes full M=64 as 4 MFMA tiles; waves reduce
// their K-partials through LDS at the end.
// mfma_f32_16x16x32_f16: A/B frag (idx=lane&15, k=quad*8+j); D row=quad*4+i,
// col=lane&15  [verified in round 2].
// Per K=32 step, each lane dequantizes its 8-run [p, p+8): moving-pointer
// scan over the block's sorted outliers (qv cached in a register, loads only
// on consume), per-element compacted index i_e = p+e - cum[b] - lt - c_e.
// ---------------------------------------------------------------------------
__global__ __launch_bounds__(256) void fused_gemm_kernel(
    const _Float16* __restrict__ x16, const int* __restrict__ i8,
    const float* __restrict__ fpdat, const int* __restrict__ fppos,
    const float* __restrict__ scales, const float* __restrict__ bias,
    const int* __restrict__ cum, float* __restrict__ out, int n8, int nf) {
  __shared__ float red[4 * 64 * 16];  // [wave][m][n] partials, 16 KB

  const int tid  = threadIdx.x;
  const int wave = tid >> 6;
  const int lane = tid & 63;
  const int quad = lane >> 4;
  const int ln   = lane & 15;
  const int n0   = blockIdx.x * 16;

  const int r = n0 + ln;        // W row (output feature) this lane dequants
  const int b = r * 4 + wave;   // its quant block for the whole K-stripe
  const int base = cum[b];
  const int nxt  = cum[b + 1];
  const float s  = scales[b];
  const int n8m1 = n8 - 1;

  // Moving-pointer outlier scan state (register-cached head entry).
  int j  = base;
  int qv = (j < nxt) ? fppos[j] : 0x7fffffff;
  float fv = (j < nxt) ? fpdat[j] : 0.f;
  int lt = 0;  // outliers in [block_start, p)

  floatx4 acc0 = {0,0,0,0}, acc1 = {0,0,0,0}, acc2 = {0,0,0,0}, acc3 = {0,0,0,0};
  float ov[8];
#pragma unroll
  for (int e = 0; e < 8; ++e) ov[e] = 0.f;

  const int kbase = wave * 1024 + quad * 8;

  for (int st = 0; st < 32; ++st) {
    const int k = kbase + st * 32;       // global k of this lane's 8-run
    const int p = r * INF + k;           // flat W position of run start

    // Consume sorted outliers below p+8. Entries < p only bump lt; entries
    // in [p, p+8) set a slot flag + value. Typical step: 1 compare, 0 loads.
    int f = 0;
    while (qv < p + 8) {
      if (qv < p) {
        ++lt;
      } else {
        const int d = qv - p;
        f |= (1 << d);
#pragma unroll
        for (int e = 0; e < 8; ++e) ov[e] = (d == e) ? fv : ov[e];
      }
      ++j;
      qv = (j < nxt) ? fppos[j] : 0x7fffffff;
      fv = (j < nxt) ? fpdat[j] : 0.f;
    }

    // Dequantize the 8-run from the compacted int8 stream.
    const int i0 = p - base - lt;  // compacted index of position p (if non-outlier)
    half8 bh;
    int c = 0;  // flags in [0, e)
#pragma unroll
    for (int e = 0; e < 8; ++e) {
      int ie = i0 + e - c;
      if (ie > n8m1) ie = n8m1;          // trailing-outlier guard
      const float vq = (float)i8[ie] * s;
      const int flg = (f >> e) & 1;
      bh[e] = (_Float16)(flg ? ov[e] : vq);
      c += flg;
    }
    lt += c;  // consumed in-run entries are below all future p

    // A-fragments (L2-resident x16) + 4 MFMA tiles (M = 64).
    const half8 a0 = *(const half8*)&x16[(0 * 16 + ln) * INF + k];
    const half8 a1 = *(const half8*)&x16[(1 * 16 + ln) * INF + k];
    const half8 a2 = *(const half8*)&x16[(2 * 16 + ln) * INF + k];
    const half8 a3 = *(const half8*)&x16[(3 * 16 + ln) * INF + k];
    acc0 = __builtin_amdgcn_mfma_f32_16x16x32_f16(a0, bh, acc0, 0, 0, 0);
    acc1 = __builtin_amdgcn_mfma_f32_16x16x32_f16(a1, bh, acc1, 0, 0, 0);
    acc2 = __builtin_amdgcn_mfma_f32_16x16x32_f16(a2, bh, acc2, 0, 0, 0);
    acc3 = __builtin_amdgcn_mfma_f32_16x16x32_f16(a3, bh, acc3, 0, 0, 0);
  }

  // Cross-wave K-reduction. Lane holds C[t*16 + quad*4 + i][ln] for tile t.
  const int mb = quad * 4;
#pragma unroll
  for (int i = 0; i < 4; ++i) red[wave * 1024 + (0 * 16 + mb + i) * 16 + ln] = acc0[i];
#pragma unroll
  for (int i = 0; i < 4; ++i) red[wave * 1024 + (1 * 16 + mb + i) * 16 + ln] = acc1[i];
#pragma unroll
  for (int i = 0; i < 4; ++i) red[wave * 1024 + (2 * 16 + mb + i) * 16 + ln] = acc2[i];
#pragma unroll
  for (int i = 0; i < 4; ++i) red[wave * 1024 + (3 * 16 + mb + i) * 16 + ln] = acc3[i];
  __syncthreads();

#pragma unroll
  for (int c2 = 0; c2 < 4; ++c2) {
    const int cell = tid + c2 * 256;       // 1024 cells = 64 m x 16 n
    const int m = cell >> 4, n = cell & 15;
    const float v = red[cell] + red[1024 + cell] + red[2048 + cell] +
                    red[3072 + cell] + bias[n0 + n];
    out[m * OUTF + n0 + n] = v;
  }
}

// ---------------------------------------------------------------------------
// Inputs: 0 x(fp32) 1 int8_data(i32) 2 fp16_data(fp32) 3 scales(fp32)
// 4 bias(fp32) 5 int8_pos(i32, UNUSED) 6 fp16_pos(i32) 7 block_idx(UNUSED)
// ws: x16 (512 KB) | cum (int[44033])
// ---------------------------------------------------------------------------
extern "C" void kernel_launch(void* const* d_in, const int* in_sizes, int n_in,
                              void* d_out, int out_size, void* d_ws,
                              size_t ws_size, hipStream_t stream) {
  const float* x      = (const float*)d_in[0];
  const int*   i8     = (const int*)d_in[1];
  const float* fpdat  = (const float*)d_in[2];
  const float* scales = (const float*)d_in[3];
  const float* bias   = (const float*)d_in[4];
  const int*   fppos  = (const int*)d_in[6];

  _Float16* x16 = (_Float16*)d_ws;
  int*      cum = (int*)((char*)d_ws + (size_t)TOK * INF * sizeof(_Float16));
  float*    out = (float*)d_out;

  const int nf = in_sizes[2];
  const int n8 = in_sizes[1];

  precompute_kernel<<<256, 256, 0, stream>>>(x, fppos, nf, x16, cum);
  fused_gemm_kernel<<<NBLK, 256, 0, stream>>>(x16, i8, fpdat, fppos, scales,
                                              bias, cum, out, n8, nf);
}

// Round 4
// 538.506 us; speedup vs baseline: 1.0291x; 1.0291x over previous
//
#include <hip/hip_runtime.h>
#include <hip/hip_fp16.h>

// Fixed problem shape
#define TOK   64
#define INF   4096
#define OUTF  11008
#define NQB   44032            // numel/1024 quant blocks
#define NBLK  (OUTF / 16)      // 688 GEMM blocks

// Harness dtypes: fp16 arrays arrive as fp32; ints as int32; output fp32.
typedef __attribute__((ext_vector_type(8))) _Float16 half8;
typedef __attribute__((ext_vector_type(4))) _Float16 half4;
typedef __attribute__((ext_vector_type(4))) float floatx4;

__device__ __forceinline__ int lower_bound(const int* __restrict__ a, int n,
                                           int target) {
  int lo = 0, hi = n;
  while (lo < hi) {
    const int mid = (lo + hi) >> 1;
    if (a[mid] < target) lo = mid + 1; else hi = mid;
  }
  return lo;
}

// ---------------------------------------------------------------------------
// x fp32 -> fp16 once (512 KB, L2-resident for the GEMM). 256x256 = 65536
// threads x 4 elems = TOK*INF.
// ---------------------------------------------------------------------------
__global__ __launch_bounds__(256) void xconv_kernel(
    const float* __restrict__ x, _Float16* __restrict__ x16) {
  const int t = blockIdx.x * 256 + threadIdx.x;
  const floatx4 f = *(const floatx4*)&x[t * 4];
  half4 h;
  h[0] = (_Float16)f[0]; h[1] = (_Float16)f[1];
  h[2] = (_Float16)f[2]; h[3] = (_Float16)f[3];
  *(half4*)&x16[t * 4] = h;
}

// ---------------------------------------------------------------------------
// Block-centric dequant: workgroup = quant block b (1024 positions), thread =
// 4 consecutive positions. Outlier range [base,nxt) found by two wave-uniform
// binary searches on sorted fp16_pos (L2-resident; int8_pos 180 MB never
// read). Compacted index of non-outlier position p: p - base - lt_local(p).
// Reads: 4 near-contiguous i8 dwords/thread (lanes line-covered);
// writes: 8 B contiguous fp16/thread. Fully coalesced both ways.
// ---------------------------------------------------------------------------
__global__ __launch_bounds__(256) void dequant_kernel(
    const int* __restrict__ i8, const float* __restrict__ fpdat,
    const int* __restrict__ fppos, const float* __restrict__ scales,
    _Float16* __restrict__ W, int n8, int nf) {
  const int b   = blockIdx.x;
  const int pb  = b << 10;               // block start position
  const int base = lower_bound(fppos, nf, pb);
  const int nxt  = lower_bound(fppos, nf, pb + 1024);
  const float s  = scales[b];

  const int p0 = pb + threadIdx.x * 4;   // this thread's 4 positions

  // Scan the block's outliers (avg ~2.8): count below p0, capture in-run hits.
  int lt = 0, f = 0;
  float ov0 = 0.f, ov1 = 0.f, ov2 = 0.f, ov3 = 0.f;
  for (int j = base; j < nxt; ++j) {
    const int   d = fppos[j] - p0;
    const float v = fpdat[j];
    lt += (d < 0);
    ov0 = (d == 0) ? v : ov0;  ov1 = (d == 1) ? v : ov1;
    ov2 = (d == 2) ? v : ov2;  ov3 = (d == 3) ? v : ov3;
    f |= ((unsigned)d < 4u) ? (1 << d) : 0;
  }

  // Compacted stream: 4 contiguous candidates starting at i0 (clamped tail).
  const int i0 = p0 - base - lt;
  const int m  = n8 - 1;
  const int l0 = i8[i0 + 0 > m ? m : i0 + 0];
  const int l1 = i8[i0 + 1 > m ? m : i0 + 1];
  const int l2 = i8[i0 + 2 > m ? m : i0 + 2];
  const int l3 = i8[i0 + 3 > m ? m : i0 + 3];

  // Emit: walk read-pointer q through l0..l3, outlier slots take fp values.
  half4 o;
  int q = 0;
  {
    const int flg = f & 1;
    o[0] = flg ? (_Float16)ov0 : (_Float16)((float)l0 * s);
    q += 1 - flg;
  }
  {
    const int flg = (f >> 1) & 1;
    const int lv  = (q == 0) ? l0 : l1;
    o[1] = flg ? (_Float16)ov1 : (_Float16)((float)lv * s);
    q += 1 - flg;
  }
  {
    const int flg = (f >> 2) & 1;
    const int lv  = (q == 0) ? l0 : (q == 1) ? l1 : l2;
    o[2] = flg ? (_Float16)ov2 : (_Float16)((float)lv * s);
    q += 1 - flg;
  }
  {
    const int flg = (f >> 3) & 1;
    const int lv  = (q == 0) ? l0 : (q == 1) ? l1 : (q == 2) ? l2 : l3;
    o[3] = flg ? (_Float16)ov3 : (_Float16)((float)lv * s);
  }
  *(half4*)&W[p0] = o;
}

// ---------------------------------------------------------------------------
// GEMM: out = x @ W^T + bias. Barrier-free K-loop: block = 16 output
// features, 4 waves = K-quarters (1024 each), wave does full M=64 as 4 MFMA
// tiles; B-frag = plain half8 streaming load from W, A-frags from x16
// (L2-resident). Cross-wave K-reduction through LDS at the end.
// mfma_f32_16x16x32_f16: A/B frag idx=lane&15, k=quad*8+j; D row=quad*4+i,
// col=lane&15  [verified rounds 2-3].
// ---------------------------------------------------------------------------
__global__ __launch_bounds__(256) void gemm_kernel(
    const _Float16* __restrict__ x16, const _Float16* __restrict__ W,
    const float* __restrict__ bias, float* __restrict__ out) {
  __shared__ float red[4 * 64 * 16];  // [wave][m][n] partials, 16 KB

  const int tid  = threadIdx.x;
  const int wave = tid >> 6;
  const int lane = tid & 63;
  const int quad = lane >> 4;
  const int ln   = lane & 15;
  const int n0   = blockIdx.x * 16;

  const int r     = n0 + ln;                  // W row this lane streams
  const int kbase = wave * 1024 + quad * 8;

  floatx4 acc0 = {0,0,0,0}, acc1 = {0,0,0,0}, acc2 = {0,0,0,0}, acc3 = {0,0,0,0};

  const _Float16* wp = &W[r * INF + kbase];
  const _Float16* ap = &x16[ln * INF + kbase];

#pragma unroll 4
  for (int st = 0; st < 32; ++st) {
    const int k = st * 32;
    const half8 bh = *(const half8*)&wp[k];
    const half8 a0 = *(const half8*)&ap[k];
    const half8 a1 = *(const half8*)&ap[16 * INF + k];
    const half8 a2 = *(const half8*)&ap[32 * INF + k];
    const half8 a3 = *(const half8*)&ap[48 * INF + k];
    acc0 = __builtin_amdgcn_mfma_f32_16x16x32_f16(a0, bh, acc0, 0, 0, 0);
    acc1 = __builtin_amdgcn_mfma_f32_16x16x32_f16(a1, bh, acc1, 0, 0, 0);
    acc2 = __builtin_amdgcn_mfma_f32_16x16x32_f16(a2, bh, acc2, 0, 0, 0);
    acc3 = __builtin_amdgcn_mfma_f32_16x16x32_f16(a3, bh, acc3, 0, 0, 0);
  }

  // Cross-wave K-reduction. Lane holds C[t*16 + quad*4 + i][ln] for tile t.
  const int mb = quad * 4;
#pragma unroll
  for (int i = 0; i < 4; ++i) red[wave * 1024 + (mb + i)      * 16 + ln] = acc0[i];
#pragma unroll
  for (int i = 0; i < 4; ++i) red[wave * 1024 + (16 + mb + i) * 16 + ln] = acc1[i];
#pragma unroll
  for (int i = 0; i < 4; ++i) red[wave * 1024 + (32 + mb + i) * 16 + ln] = acc2[i];
#pragma unroll
  for (int i = 0; i < 4; ++i) red[wave * 1024 + (48 + mb + i) * 16 + ln] = acc3[i];
  __syncthreads();

#pragma unroll
  for (int c2 = 0; c2 < 4; ++c2) {
    const int cell = tid + c2 * 256;  // 1024 cells = 64 m x 16 n
    const int mm = cell >> 4, nn = cell & 15;
    const float v = red[cell] + red[1024 + cell] + red[2048 + cell] +
                    red[3072 + cell] + bias[n0 + nn];
    out[mm * OUTF + n0 + nn] = v;
  }
}

// ---------------------------------------------------------------------------
// Inputs: 0 x(fp32) 1 int8_data(i32) 2 fp16_data(fp32) 3 scales(fp32)
// 4 bias(fp32) 5 int8_pos(UNUSED) 6 fp16_pos(i32) 7 block_idx(UNUSED)
// ws: W fp16 (90.2 MB) | x16 (512 KB)
// ---------------------------------------------------------------------------
extern "C" void kernel_launch(void* const* d_in, const int* in_sizes, int n_in,
                              void* d_out, int out_size, void* d_ws,
                              size_t ws_size, hipStream_t stream) {
  const float* x      = (const float*)d_in[0];
  const int*   i8     = (const int*)d_in[1];
  const float* fpdat  = (const float*)d_in[2];
  const float* scales = (const float*)d_in[3];
  const float* bias   = (const float*)d_in[4];
  const int*   fppos  = (const int*)d_in[6];

  _Float16* W   = (_Float16*)d_ws;
  _Float16* x16 = (_Float16*)((char*)d_ws + (size_t)OUTF * INF * sizeof(_Float16));
  float*    out = (float*)d_out;

  const int n8 = in_sizes[1];
  const int nf = in_sizes[2];

  xconv_kernel<<<(TOK * INF) / 1024, 256, 0, stream>>>(x, x16);
  dequant_kernel<<<NQB, 256, 0, stream>>>(i8, fpdat, fppos, scales, W, n8, nf);
  gemm_kernel<<<NBLK, 256, 0, stream>>>(x16, W, bias, out);
}

// Round 5
// 480.345 us; speedup vs baseline: 1.1537x; 1.1211x over previous
//
#include <hip/hip_runtime.h>
#include <hip/hip_fp16.h>

// Fixed problem shape
#define TOK   64
#define INF   4096
#define OUTF  11008
#define NQB   44032            // numel/1024 quant blocks
#define NBLK  (OUTF / 16)      // 688 GEMM blocks

// Harness dtypes: fp16 arrays arrive as fp32; ints as int32; output fp32.
typedef __attribute__((ext_vector_type(8))) _Float16 half8;
typedef __attribute__((ext_vector_type(4))) _Float16 half4;
typedef __attribute__((ext_vector_type(4))) float floatx4;

// ---------------------------------------------------------------------------
// Precompute (one 256x256 launch, ~3 us):
//  (a) x fp32 -> fp16 (512 KB, L2-resident for the GEMM)
//  (b) cum[b] = lower_bound(fp16_pos, b*1024) — 44033 INDEPENDENT binary
//      searches, latency fully overlapped across threads. R4's per-workgroup
//      search (52 dependent L2 loads x 44032 blocks) was the latency wall.
// ---------------------------------------------------------------------------
__global__ __launch_bounds__(256) void precompute_kernel(
    const float* __restrict__ x, const int* __restrict__ fppos, int nf,
    _Float16* __restrict__ x16, int* __restrict__ cum) {
  const int t = blockIdx.x * 256 + threadIdx.x;
  {
    const floatx4 f = *(const floatx4*)&x[t * 4];
    half4 h;
    h[0] = (_Float16)f[0]; h[1] = (_Float16)f[1];
    h[2] = (_Float16)f[2]; h[3] = (_Float16)f[3];
    *(half4*)&x16[t * 4] = h;
  }
  if (t <= NQB) {
    const int target = t << 10;
    int lo = 0, hi = nf;  // first index with fppos[idx] >= target
    while (lo < hi) {
      const int mid = (lo + hi) >> 1;
      if (fppos[mid] < target) lo = mid + 1; else hi = mid;
    }
    cum[t] = lo;
  }
}

// ---------------------------------------------------------------------------
// Block-centric dequant: workgroup = quant block b, thread = 4 consecutive
// positions. Outlier range [cum[b], cum[b+1]) read from the precomputed
// L2-resident table (2 loads — no binary search chain). Compacted index of
// non-outlier position p: p - base - (#outliers in [pb, p)).
// ---------------------------------------------------------------------------
__global__ __launch_bounds__(256) void dequant_kernel(
    const int* __restrict__ i8, const float* __restrict__ fpdat,
    const int* __restrict__ fppos, const float* __restrict__ scales,
    const int* __restrict__ cum, _Float16* __restrict__ W, int n8) {
  const int b    = blockIdx.x;
  const int pb   = b << 10;              // block start position
  const int base = cum[b];
  const int nxt  = cum[b + 1];
  const float s  = scales[b];

  const int p0 = pb + threadIdx.x * 4;   // this thread's 4 positions

  // Scan the block's outliers (avg ~2.8, wave-uniform broadcast loads).
  int lt = 0, f = 0;
  float ov0 = 0.f, ov1 = 0.f, ov2 = 0.f, ov3 = 0.f;
  for (int j = base; j < nxt; ++j) {
    const int   d = fppos[j] - p0;
    const float v = fpdat[j];
    lt += (d < 0);
    ov0 = (d == 0) ? v : ov0;  ov1 = (d == 1) ? v : ov1;
    ov2 = (d == 2) ? v : ov2;  ov3 = (d == 3) ? v : ov3;
    f |= ((unsigned)d < 4u) ? (1 << d) : 0;
  }

  // Compacted stream: 4 contiguous candidates starting at i0 (clamped tail).
  const int i0 = p0 - base - lt;
  const int m  = n8 - 1;
  const int l0 = i8[i0 + 0 > m ? m : i0 + 0];
  const int l1 = i8[i0 + 1 > m ? m : i0 + 1];
  const int l2 = i8[i0 + 2 > m ? m : i0 + 2];
  const int l3 = i8[i0 + 3 > m ? m : i0 + 3];

  // Emit: walk read-pointer q through l0..l3; outlier slots take fp values.
  half4 o;
  int q = 0;
  {
    const int flg = f & 1;
    o[0] = flg ? (_Float16)ov0 : (_Float16)((float)l0 * s);
    q += 1 - flg;
  }
  {
    const int flg = (f >> 1) & 1;
    const int lv  = (q == 0) ? l0 : l1;
    o[1] = flg ? (_Float16)ov1 : (_Float16)((float)lv * s);
    q += 1 - flg;
  }
  {
    const int flg = (f >> 2) & 1;
    const int lv  = (q == 0) ? l0 : (q == 1) ? l1 : l2;
    o[2] = flg ? (_Float16)ov2 : (_Float16)((float)lv * s);
    q += 1 - flg;
  }
  {
    const int flg = (f >> 3) & 1;
    const int lv  = (q == 0) ? l0 : (q == 1) ? l1 : (q == 2) ? l2 : l3;
    o[3] = flg ? (_Float16)ov3 : (_Float16)((float)lv * s);
  }
  *(half4*)&W[p0] = o;
}

// ---------------------------------------------------------------------------
// GEMM: out = x @ W^T + bias. Barrier-free K-loop (unchanged from R4):
// block = 16 output features, 4 waves = K-quarters, wave does full M=64 as
// 4 MFMA tiles; cross-wave K-reduction through LDS at the end.
// mfma_f32_16x16x32_f16: A/B frag idx=lane&15, k=quad*8+j; D row=quad*4+i,
// col=lane&15  [verified rounds 2-4].
// ---------------------------------------------------------------------------
__global__ __launch_bounds__(256) void gemm_kernel(
    const _Float16* __restrict__ x16, const _Float16* __restrict__ W,
    const float* __restrict__ bias, float* __restrict__ out) {
  __shared__ float red[4 * 64 * 16];  // [wave][m][n] partials, 16 KB

  const int tid  = threadIdx.x;
  const int wave = tid >> 6;
  const int lane = tid & 63;
  const int quad = lane >> 4;
  const int ln   = lane & 15;
  const int n0   = blockIdx.x * 16;

  const int r     = n0 + ln;                  // W row this lane streams
  const int kbase = wave * 1024 + quad * 8;

  floatx4 acc0 = {0,0,0,0}, acc1 = {0,0,0,0}, acc2 = {0,0,0,0}, acc3 = {0,0,0,0};

  const _Float16* wp = &W[r * INF + kbase];
  const _Float16* ap = &x16[ln * INF + kbase];

#pragma unroll 4
  for (int st = 0; st < 32; ++st) {
    const int k = st * 32;
    const half8 bh = *(const half8*)&wp[k];
    const half8 a0 = *(const half8*)&ap[k];
    const half8 a1 = *(const half8*)&ap[16 * INF + k];
    const half8 a2 = *(const half8*)&ap[32 * INF + k];
    const half8 a3 = *(const half8*)&ap[48 * INF + k];
    acc0 = __builtin_amdgcn_mfma_f32_16x16x32_f16(a0, bh, acc0, 0, 0, 0);
    acc1 = __builtin_amdgcn_mfma_f32_16x16x32_f16(a1, bh, acc1, 0, 0, 0);
    acc2 = __builtin_amdgcn_mfma_f32_16x16x32_f16(a2, bh, acc2, 0, 0, 0);
    acc3 = __builtin_amdgcn_mfma_f32_16x16x32_f16(a3, bh, acc3, 0, 0, 0);
  }

  // Cross-wave K-reduction. Lane holds C[t*16 + quad*4 + i][ln] for tile t.
  const int mb = quad * 4;
#pragma unroll
  for (int i = 0; i < 4; ++i) red[wave * 1024 + (mb + i)      * 16 + ln] = acc0[i];
#pragma unroll
  for (int i = 0; i < 4; ++i) red[wave * 1024 + (16 + mb + i) * 16 + ln] = acc1[i];
#pragma unroll
  for (int i = 0; i < 4; ++i) red[wave * 1024 + (32 + mb + i) * 16 + ln] = acc2[i];
#pragma unroll
  for (int i = 0; i < 4; ++i) red[wave * 1024 + (48 + mb + i) * 16 + ln] = acc3[i];
  __syncthreads();

#pragma unroll
  for (int c2 = 0; c2 < 4; ++c2) {
    const int cell = tid + c2 * 256;  // 1024 cells = 64 m x 16 n
    const int mm = cell >> 4, nn = cell & 15;
    const float v = red[cell] + red[1024 + cell] + red[2048 + cell] +
                    red[3072 + cell] + bias[n0 + nn];
    out[mm * OUTF + n0 + nn] = v;
  }
}

// ---------------------------------------------------------------------------
// Inputs: 0 x(fp32) 1 int8_data(i32) 2 fp16_data(fp32) 3 scales(fp32)
// 4 bias(fp32) 5 int8_pos(UNUSED) 6 fp16_pos(i32) 7 block_idx(UNUSED)
// ws: W fp16 (90.2 MB) | x16 (512 KB) | cum (int[44033], 176 KB)
// ---------------------------------------------------------------------------
extern "C" void kernel_launch(void* const* d_in, const int* in_sizes, int n_in,
                              void* d_out, int out_size, void* d_ws,
                              size_t ws_size, hipStream_t stream) {
  const float* x      = (const float*)d_in[0];
  const int*   i8     = (const int*)d_in[1];
  const float* fpdat  = (const float*)d_in[2];
  const float* scales = (const float*)d_in[3];
  const float* bias   = (const float*)d_in[4];
  const int*   fppos  = (const int*)d_in[6];

  char* wsp = (char*)d_ws;
  _Float16* W   = (_Float16*)wsp;
  _Float16* x16 = (_Float16*)(wsp + (size_t)OUTF * INF * sizeof(_Float16));
  int*      cum = (int*)(wsp + (size_t)OUTF * INF * sizeof(_Float16)
                             + (size_t)TOK * INF * sizeof(_Float16));
  float*    out = (float*)d_out;

  const int n8 = in_sizes[1];
  const int nf = in_sizes[2];

  precompute_kernel<<<256, 256, 0, stream>>>(x, fppos, nf, x16, cum);
  dequant_kernel<<<NQB, 256, 0, stream>>>(i8, fpdat, fppos, scales, cum, W, n8);
  gemm_kernel<<<NBLK, 256, 0, stream>>>(x16, W, bias, out);
}